// Round 3
// baseline (141.267 us; speedup 1.0000x reference)
//
#include <hip/hip_runtime.h>

#define R 192
#define BATCH 1024
#define TILE 16
#define NT (R / TILE)       // 12 tiles per dimension
#define NBITWORDS (R * 6)   // 192 rows x 6 uint32 (192 bits) per row
#define NBLOCKS (BATCH * 2) // main-kernel grid size
#define PARTIALS_OFF (4 + NBITWORDS)  // float offset of per-block partials (16B aligned)

// ws layout: ws[0]                : uint32 completion counter (zeroed by build_mask)
//            ws[4 .. 4+1152)      : uint32 adjacency bitmask [R][6], triu-baked
//                                   (bit j of row i set iff j>i && adj[i][j]>0)
//            ws[1156 .. +2048*4)  : per-block float4 partials
//                                   (mse_p, mse_s, overlap, adj) — NO contended atomics.

__global__ __launch_bounds__(256) void build_mask_kernel(
    const int* __restrict__ adj, float* __restrict__ ws)
{
    unsigned int* wsbits = (unsigned int*)(ws + 4);
    const int e = blockIdx.x * 256 + threadIdx.x;   // 0 .. R*R-1
    if (e == 0) *(unsigned int*)ws = 0u;            // reset last-block counter
    if (e >= R * R) return;
    const int i = e / R;
    const int j = e - i * R;
    const bool pred = (adj[e] > 0) && (j > i);
    const unsigned long long m = __ballot(pred);
    const int lane = e & 63;
    if (lane == 0)  wsbits[e >> 5] = (unsigned int)m;
    if (lane == 32) wsbits[e >> 5] = (unsigned int)(m >> 32);
}

// Fully-unrolled tile sweep. SEL picks the tj-parity stripe. All tile indices
// are compile-time constants after unrolling: addresses fold to immediate LDS
// offsets, the (i<j) predicate exists only in diagonal bodies, and the
// adjacency-row words are register-resident with static indexing.
template<int SEL>
__device__ __forceinline__ void tile_loop(
    const float4* __restrict__ room, const float2* __restrict__ cent,
    const unsigned int* __restrict__ sadj,
    const int li, const int lj, float& ov, float& ad)
{
    const unsigned int shlo = (unsigned int)lj;        // bit pos, even tj
    const unsigned int shhi = (unsigned int)lj + 16u;  // bit pos, odd tj
    #pragma unroll
    for (int ti = 0; ti < NT; ++ti) {
        const int i = ti * TILE + li;
        const float4 ri = room[i];   // x, y, x+w, y+h (precomputed)
        const float2 ci = cent[i];   // cx, cy          (precomputed)
        unsigned int mrow[6];        // adjacency row words in regs (unused DCE)
        #pragma unroll
        for (int k = 0; k < 6; ++k) mrow[k] = sadj[i * 6 + k];
        #pragma unroll
        for (int tj = ti + SEL; tj < NT; tj += 2) {
            const int j = tj * TILE + lj;
            const float4 rj = room[j];
            const float2 cj = cent[j];
            float ow = fminf(ri.z, rj.z) - fmaxf(ri.x, rj.x);
            float oh = fminf(ri.w, rj.w) - fmaxf(ri.y, rj.y);
            ow = fmaxf(ow, 0.0f);
            oh = fmaxf(oh, 0.0f);
            const float area = ow * oh;
            if (tj == ti) {                 // compile-time branch: diagonal tile
                ov += (lj > li) ? area : 0.0f;
            } else {                        // strict upper tile: no predicate
                ov += area;
            }
            const unsigned int bits = mrow[tj >> 1];          // static index
            const unsigned int sh   = (tj & 1) ? shhi : shlo; // static select
            const float bitf = (float)((bits >> sh) & 1u);    // v_bfe + v_cvt
            const float dx = ci.x - cj.x;
            const float dy = ci.y - cj.y;
            const float sq = fmaf(dx, dx, dy * dy);
            ad = fmaf(__builtin_amdgcn_sqrtf(sq), bitf, ad);  // triu baked in mask
        }
    }
}

__global__ __launch_bounds__(256) void floorplan_main_kernel(
    const float* __restrict__ pos,    // [B,R,2]
    const float* __restrict__ siz,    // [B,R,2]
    const float* __restrict__ tpos,   // [B,R,2]
    const float* __restrict__ tsiz,   // [B,R,2]
    float* __restrict__ ws,
    float* __restrict__ out)
{
    __shared__ float4 room[R];              // x, y, x+w, y+h
    __shared__ float2 cent[R];              // cx, cy
    __shared__ unsigned int sadj[NBITWORDS];
    __shared__ float wsum[4][4];
    __shared__ bool lastflag;

    const int b   = blockIdx.x;
    const int sel = blockIdx.y;             // 0/1 : tj-stripe parity
    const int tid = threadIdx.x;

    const float2* pb  = (const float2*)(pos  + (size_t)b * (R * 2));
    const float2* sb  = (const float2*)(siz  + (size_t)b * (R * 2));
    const float2* tpb = (const float2*)(tpos + (size_t)b * (R * 2));
    const float2* tsb = (const float2*)(tsiz + (size_t)b * (R * 2));
    const unsigned int* wsbits = (const unsigned int*)(ws + 4);

    float mse_p = 0.0f, mse_s = 0.0f;

    // Stage rooms + derived extents/centers; MSE only on the sel==0 stripe.
    if (tid < R) {
        const float2 p = pb[tid];
        const float2 s = sb[tid];
        room[tid] = make_float4(p.x, p.y, p.x + s.x, p.y + s.y);
        cent[tid] = make_float2(fmaf(0.5f, s.x, p.x), fmaf(0.5f, s.y, p.y));
        if (sel == 0) {
            const float2 tp = tpb[tid];
            const float2 ts = tsb[tid];
            const float dpx = p.x - tp.x, dpy = p.y - tp.y;
            const float dsx = s.x - ts.x, dsy = s.y - ts.y;
            mse_p = fmaf(dpx, dpx, dpy * dpy);
            mse_s = fmaf(dsx, dsx, dsy * dsy);
        }
    }
    // Stage adjacency bitmask (1152 words / 256 threads).
    for (int w = tid; w < NBITWORDS; w += 256) sadj[w] = wsbits[w];
    __syncthreads();

    float ov = 0.0f, ad = 0.0f;
    const int li = tid >> 4;    // 0..15 : i within tile
    const int lj = tid & 15;    // 0..15 : j within tile

    if (sel == 0) tile_loop<0>(room, cent, sadj, li, lj, ov, ad);
    else          tile_loop<1>(room, cent, sadj, li, lj, ov, ad);

    // Reduce 4 accumulators: 64-lane shuffle, then cross-wave via LDS.
    for (int off = 32; off > 0; off >>= 1) {
        mse_p += __shfl_down(mse_p, off);
        mse_s += __shfl_down(mse_s, off);
        ov    += __shfl_down(ov, off);
        ad    += __shfl_down(ad, off);
    }
    const int wid  = tid >> 6;
    const int lane = tid & 63;
    if (lane == 0) {
        wsum[wid][0] = mse_p;
        wsum[wid][1] = mse_s;
        wsum[wid][2] = ov;
        wsum[wid][3] = ad;
    }
    __syncthreads();
    // Per-block private partial slot (contended atomics cost 34us of tail before).
    if (tid < 4) {
        const float v = wsum[0][tid] + wsum[1][tid] + wsum[2][tid] + wsum[3][tid];
        const int blk = sel * BATCH + b;
        ws[PARTIALS_OFF + blk * 4 + tid] = v;   // one coalesced 16B store
    }
    __syncthreads();   // drains vmcnt: the 4 partial stores are issued

    // Last-block-done finalize: saves a whole kernel dispatch (+gap).
    if (tid == 0) {
        __threadfence();   // release: partials visible device-wide before counter bump
        const unsigned int old = __hip_atomic_fetch_add(
            (unsigned int*)ws, 1u, __ATOMIC_ACQ_REL, __HIP_MEMORY_SCOPE_AGENT);
        lastflag = (old == NBLOCKS - 1);
    }
    __syncthreads();
    if (!lastflag) return;

    // One (cold) block reduces all 2048 float4 partials.
    __threadfence();   // acquire: don't read stale L1/L2 across XCDs
    float a0 = 0.0f, a1 = 0.0f, a2 = 0.0f, a3 = 0.0f;
    for (int k = tid; k < NBLOCKS; k += 256) {
        const float* p = ws + PARTIALS_OFF + k * 4;
        a0 += __hip_atomic_load(p + 0, __ATOMIC_RELAXED, __HIP_MEMORY_SCOPE_AGENT);
        a1 += __hip_atomic_load(p + 1, __ATOMIC_RELAXED, __HIP_MEMORY_SCOPE_AGENT);
        a2 += __hip_atomic_load(p + 2, __ATOMIC_RELAXED, __HIP_MEMORY_SCOPE_AGENT);
        a3 += __hip_atomic_load(p + 3, __ATOMIC_RELAXED, __HIP_MEMORY_SCOPE_AGENT);
    }
    for (int off = 32; off > 0; off >>= 1) {
        a0 += __shfl_down(a0, off);
        a1 += __shfl_down(a1, off);
        a2 += __shfl_down(a2, off);
        a3 += __shfl_down(a3, off);
    }
    if (lane == 0) {
        wsum[wid][0] = a0;
        wsum[wid][1] = a1;
        wsum[wid][2] = a2;
        wsum[wid][3] = a3;
    }
    __syncthreads();
    if (tid == 0) {
        float s0 = 0.0f, s1 = 0.0f, s2 = 0.0f, s3 = 0.0f;
        #pragma unroll
        for (int w = 0; w < 4; ++w) {
            s0 += wsum[w][0]; s1 += wsum[w][1]; s2 += wsum[w][2]; s3 += wsum[w][3];
        }
        const float invN = 1.0f / (float)(BATCH * R * 2);
        const float invB = 1.0f / (float)BATCH;
        const float pos_loss  = s0 * invN;
        const float size_loss = s1 * invN;
        const float overlap   = s2 * invB;
        const float adjl      = s3 * invB;
        out[0] = pos_loss + size_loss + 0.5f * overlap + 0.3f * adjl;
        out[1] = pos_loss;
        out[2] = size_loss;
        out[3] = overlap;
        out[4] = adjl;
    }
}

extern "C" void kernel_launch(void* const* d_in, const int* in_sizes, int n_in,
                              void* d_out, int out_size, void* d_ws, size_t ws_size,
                              hipStream_t stream) {
    const float* pos  = (const float*)d_in[0];
    const float* siz  = (const float*)d_in[1];
    const float* tpos = (const float*)d_in[2];
    const float* tsiz = (const float*)d_in[3];
    const int*   adj  = (const int*)d_in[4];
    float* ws  = (float*)d_ws;
    float* out = (float*)d_out;

    hipLaunchKernelGGL(build_mask_kernel, dim3((R * R + 255) / 256), dim3(256), 0, stream,
                       adj, ws);
    hipLaunchKernelGGL(floorplan_main_kernel, dim3(BATCH, 2), dim3(256), 0, stream,
                       pos, siz, tpos, tsiz, ws, out);
}

// Round 4
// 83.612 us; speedup vs baseline: 1.6895x; 1.6895x over previous
//
#include <hip/hip_runtime.h>

#define R 192
#define BATCH 1024
#define TILE 16
#define NT (R / TILE)       // 12 tiles per dimension
#define NBITWORDS (R * 6)   // 192 rows x 6 uint32 (192 bits) per row
#define NBLOCKS (BATCH * 2) // main-kernel grid size
#define PARTIALS_OFF (4 + NBITWORDS)  // float offset of per-block partials (16B aligned)

// ws layout: ws[0..3]            : unused (legacy accumulator slots)
//            ws[4 .. 4+1152)     : uint32 adjacency bitmask [R][6], triu-baked
//                                  (bit j of row i set iff j>i && adj[i][j]>0)
//            ws[1156 .. +2048*4) : per-block float4 partials
//                                  (mse_p, mse_s, overlap, adj) — NO atomics, NO fences.
//
// R3 lesson (reverted): folding finalize into main via per-block
// __threadfence() + device-scope acq_rel counter cost ~70us of serialized
// tail (main 79us @ 31% occupancy). A separate 1-block finalize dispatch
// is far cheaper than 2048 release-fences + one contended atomic line.

__global__ __launch_bounds__(256) void build_mask_kernel(
    const int* __restrict__ adj, float* __restrict__ ws)
{
    unsigned int* wsbits = (unsigned int*)(ws + 4);
    const int e = blockIdx.x * 256 + threadIdx.x;   // 0 .. R*R-1
    if (e >= R * R) return;
    const int i = e / R;
    const int j = e - i * R;
    const bool pred = (adj[e] > 0) && (j > i);
    const unsigned long long m = __ballot(pred);
    const int lane = e & 63;
    if (lane == 0)  wsbits[e >> 5] = (unsigned int)m;
    if (lane == 32) wsbits[e >> 5] = (unsigned int)(m >> 32);
}

// Fully-unrolled tile sweep. SEL picks the tj-parity stripe. All tile indices
// are compile-time constants after unrolling: addresses fold to immediate LDS
// offsets, the (i<j) predicate exists only in diagonal bodies, and the
// adjacency-row words are register-resident with static indexing.
template<int SEL>
__device__ __forceinline__ void tile_loop(
    const float4* __restrict__ room, const float2* __restrict__ cent,
    const unsigned int* __restrict__ sadj,
    const int li, const int lj, float& ov, float& ad)
{
    const unsigned int shlo = (unsigned int)lj;        // bit pos, even tj
    const unsigned int shhi = (unsigned int)lj + 16u;  // bit pos, odd tj
    #pragma unroll
    for (int ti = 0; ti < NT; ++ti) {
        const int i = ti * TILE + li;
        const float4 ri = room[i];   // x, y, x+w, y+h (precomputed)
        const float2 ci = cent[i];   // cx, cy          (precomputed)
        unsigned int mrow[6];        // adjacency row words in regs (unused DCE)
        #pragma unroll
        for (int k = 0; k < 6; ++k) mrow[k] = sadj[i * 6 + k];
        #pragma unroll
        for (int tj = ti + SEL; tj < NT; tj += 2) {
            const int j = tj * TILE + lj;
            const float4 rj = room[j];
            const float2 cj = cent[j];
            float ow = fminf(ri.z, rj.z) - fmaxf(ri.x, rj.x);
            float oh = fminf(ri.w, rj.w) - fmaxf(ri.y, rj.y);
            ow = fmaxf(ow, 0.0f);
            oh = fmaxf(oh, 0.0f);
            const float area = ow * oh;
            if (tj == ti) {                 // compile-time branch: diagonal tile
                ov += (lj > li) ? area : 0.0f;
            } else {                        // strict upper tile: no predicate
                ov += area;
            }
            const unsigned int bits = mrow[tj >> 1];          // static index
            const unsigned int sh   = (tj & 1) ? shhi : shlo; // static select
            const float bitf = (float)((bits >> sh) & 1u);    // v_bfe + v_cvt
            const float dx = ci.x - cj.x;
            const float dy = ci.y - cj.y;
            const float sq = fmaf(dx, dx, dy * dy);
            ad = fmaf(__builtin_amdgcn_sqrtf(sq), bitf, ad);  // triu baked in mask
        }
    }
}

__global__ __launch_bounds__(256) void floorplan_main_kernel(
    const float* __restrict__ pos,    // [B,R,2]
    const float* __restrict__ siz,    // [B,R,2]
    const float* __restrict__ tpos,   // [B,R,2]
    const float* __restrict__ tsiz,   // [B,R,2]
    float* __restrict__ ws)
{
    __shared__ float4 room[R];              // x, y, x+w, y+h
    __shared__ float2 cent[R];              // cx, cy
    __shared__ unsigned int sadj[NBITWORDS];
    __shared__ float wsum[4][4];

    const int b   = blockIdx.x;
    const int sel = blockIdx.y;             // 0/1 : tj-stripe parity
    const int tid = threadIdx.x;

    const float2* pb  = (const float2*)(pos  + (size_t)b * (R * 2));
    const float2* sb  = (const float2*)(siz  + (size_t)b * (R * 2));
    const float2* tpb = (const float2*)(tpos + (size_t)b * (R * 2));
    const float2* tsb = (const float2*)(tsiz + (size_t)b * (R * 2));
    const unsigned int* wsbits = (const unsigned int*)(ws + 4);

    float mse_p = 0.0f, mse_s = 0.0f;

    // Stage rooms + derived extents/centers; MSE only on the sel==0 stripe.
    if (tid < R) {
        const float2 p = pb[tid];
        const float2 s = sb[tid];
        room[tid] = make_float4(p.x, p.y, p.x + s.x, p.y + s.y);
        cent[tid] = make_float2(fmaf(0.5f, s.x, p.x), fmaf(0.5f, s.y, p.y));
        if (sel == 0) {
            const float2 tp = tpb[tid];
            const float2 ts = tsb[tid];
            const float dpx = p.x - tp.x, dpy = p.y - tp.y;
            const float dsx = s.x - ts.x, dsy = s.y - ts.y;
            mse_p = fmaf(dpx, dpx, dpy * dpy);
            mse_s = fmaf(dsx, dsx, dsy * dsy);
        }
    }
    // Stage adjacency bitmask (1152 words / 256 threads).
    for (int w = tid; w < NBITWORDS; w += 256) sadj[w] = wsbits[w];
    __syncthreads();

    float ov = 0.0f, ad = 0.0f;
    const int li = tid >> 4;    // 0..15 : i within tile
    const int lj = tid & 15;    // 0..15 : j within tile

    if (sel == 0) tile_loop<0>(room, cent, sadj, li, lj, ov, ad);
    else          tile_loop<1>(room, cent, sadj, li, lj, ov, ad);

    // Reduce 4 accumulators: 64-lane shuffle, then cross-wave via LDS.
    for (int off = 32; off > 0; off >>= 1) {
        mse_p += __shfl_down(mse_p, off);
        mse_s += __shfl_down(mse_s, off);
        ov    += __shfl_down(ov, off);
        ad    += __shfl_down(ad, off);
    }
    const int wid  = tid >> 6;
    const int lane = tid & 63;
    if (lane == 0) {
        wsum[wid][0] = mse_p;
        wsum[wid][1] = mse_s;
        wsum[wid][2] = ov;
        wsum[wid][3] = ad;
    }
    __syncthreads();
    // Per-block private partial slot — no atomics, no fences.
    if (tid < 4) {
        const float v = wsum[0][tid] + wsum[1][tid] + wsum[2][tid] + wsum[3][tid];
        const int blk = sel * BATCH + b;
        ws[PARTIALS_OFF + blk * 4 + tid] = v;   // one coalesced 16B store
    }
}

__global__ __launch_bounds__(256) void finalize_kernel(
    const float* __restrict__ ws, float* __restrict__ out)
{
    __shared__ float wsum[4][4];
    const int tid = threadIdx.x;
    const float4* partials = (const float4*)(ws + PARTIALS_OFF);

    float a0 = 0.0f, a1 = 0.0f, a2 = 0.0f, a3 = 0.0f;
    for (int k = tid; k < NBLOCKS; k += 256) {
        const float4 v = partials[k];
        a0 += v.x; a1 += v.y; a2 += v.z; a3 += v.w;
    }
    for (int off = 32; off > 0; off >>= 1) {
        a0 += __shfl_down(a0, off);
        a1 += __shfl_down(a1, off);
        a2 += __shfl_down(a2, off);
        a3 += __shfl_down(a3, off);
    }
    const int wid  = tid >> 6;
    const int lane = tid & 63;
    if (lane == 0) {
        wsum[wid][0] = a0;
        wsum[wid][1] = a1;
        wsum[wid][2] = a2;
        wsum[wid][3] = a3;
    }
    __syncthreads();
    if (tid == 0) {
        float s0 = 0.0f, s1 = 0.0f, s2 = 0.0f, s3 = 0.0f;
        #pragma unroll
        for (int w = 0; w < 4; ++w) {
            s0 += wsum[w][0]; s1 += wsum[w][1]; s2 += wsum[w][2]; s3 += wsum[w][3];
        }
        const float invN = 1.0f / (float)(BATCH * R * 2);
        const float invB = 1.0f / (float)BATCH;
        const float pos_loss  = s0 * invN;
        const float size_loss = s1 * invN;
        const float overlap   = s2 * invB;
        const float adjl      = s3 * invB;
        out[0] = pos_loss + size_loss + 0.5f * overlap + 0.3f * adjl;
        out[1] = pos_loss;
        out[2] = size_loss;
        out[3] = overlap;
        out[4] = adjl;
    }
}

extern "C" void kernel_launch(void* const* d_in, const int* in_sizes, int n_in,
                              void* d_out, int out_size, void* d_ws, size_t ws_size,
                              hipStream_t stream) {
    const float* pos  = (const float*)d_in[0];
    const float* siz  = (const float*)d_in[1];
    const float* tpos = (const float*)d_in[2];
    const float* tsiz = (const float*)d_in[3];
    const int*   adj  = (const int*)d_in[4];
    float* ws  = (float*)d_ws;
    float* out = (float*)d_out;

    hipLaunchKernelGGL(build_mask_kernel, dim3((R * R + 255) / 256), dim3(256), 0, stream,
                       adj, ws);
    hipLaunchKernelGGL(floorplan_main_kernel, dim3(BATCH, 2), dim3(256), 0, stream,
                       pos, siz, tpos, tsiz, ws);
    hipLaunchKernelGGL(finalize_kernel, dim3(1), dim3(256), 0, stream, ws, out);
}